// Round 9
// baseline (12736.142 us; speedup 1.0000x reference)
//
#include <hip/hip_runtime.h>

// GumbelDecoderEncoder: B=16384, E=256, V=128, T=16, TAU=1.
// Key facts exploited:
//  * y is numerically EXACTLY one-hot or zero -> input matmuls are table
//    lookups (DecTab/EncTab row 128 = zero-token case).
//  * argmax(softmax((l+g)/tau)) == argmax(l+g).
//  * Encoder sieve can never fire: reconst = final encoder state.
// History: R8 split showed dec=1980us (VALU-issue-bound fp32 GRU; grid-
// limited 2 waves/SIMD) + enc~1500us (B-table traffic/latency). Spill rule
// learned R3/R4/R6: per-wave MFMA state must stay well under 128 regs.
// R9: BOTH GRUs on MFMA with one low-pressure tiling:
//  * 64 rows/block, 256 blocks, 1024 thr = 16 waves = 4 waves/SIMD (hard
//    128-reg cap from block size; wave = 1 Mtile x 12 Ntiles: acc 48 + A 12
//    + B 9 + misc ~ 110 -> fits, no spill).
//  * B-traffic 4.8GB/kernel (was 9.4-19); tables L2-resident; nontemporal
//    hints on unoise/utterance streams protect L2.
//  * dec numerics: gh via 3-way-split MFMA (error ~2^-24 rel, empirically
//    invisible: enc absmax didn't move fp32->split). logits/argmax/pointwise
//    formulas and FMA order byte-identical to the proven kernel. If absmax
//    blows to 1.0 => an argmax flipped => revert dec to fp32 next round.
// ws: 886272 floats = 3,545,088 bytes.

namespace {
constexpr int kB  = 16384;
constexpr int kE  = 256;
constexpr int kV  = 128;
constexpr int kT  = 16;
constexpr int kG3 = 768;

constexpr int kOffWe2dT  = 0;                        // [256][128] f32
constexpr int kOffDecTab = kV * kE;                  // [129][768] f32
constexpr int kOffEncTab = kOffDecTab + 129 * kG3;   // [129][768] f32
constexpr int kOffBTabE  = kOffEncTab + 129 * kG3;   // enc Whh 3-split (u16)
constexpr int kBCount    = 32 * kG3 * 8;             // 196608 u16 per level
constexpr int kOffBTabD  = kOffBTabE + (3 * kBCount) / 2;  // dec Whh 3-split
constexpr int kOffTok    = kOffBTabD + (3 * kBCount) / 2;  // [16][16384] u8
// ws floats: 820736 + 65536 = 886272  (3,545,088 bytes)
}

typedef short bf16x8 __attribute__((ext_vector_type(8)));  // 8 bf16 (4 VGPRs)
typedef float f32x4  __attribute__((ext_vector_type(4)));
typedef unsigned short u16;
typedef unsigned char u8;

__device__ __forceinline__ float sigmf(float v) { return 1.0f / (1.0f + expf(-v)); }
__device__ __forceinline__ float gumbelf(float u) {
  return -logf(-logf(u + 1e-10f) + 1e-10f);
}

__device__ __forceinline__ f32x4 mfma16(bf16x8 a, bf16x8 b, f32x4 c) {
  return __builtin_amdgcn_mfma_f32_16x16x32_bf16(a, b, c, 0, 0, 0);
}

struct Bf3 { bf16x8 h, m, l; };

// exact 3-way bf16 split: f = hi + mid + f2 (exact); lo = trunc-bf16(f2).
__device__ __forceinline__ Bf3 split3(float4 a, float4 b) {
  const float v[8] = {a.x, a.y, a.z, a.w, b.x, b.y, b.z, b.w};
  union { bf16x8 b8; u16 u[8]; } H, M, L;
#pragma unroll
  for (int e = 0; e < 8; ++e) {
    const float f = v[e];
    const unsigned hb = __float_as_uint(f) & 0xffff0000u;
    const float f1 = f - __uint_as_float(hb);
    const unsigned mb = __float_as_uint(f1) & 0xffff0000u;
    const float f2 = f1 - __uint_as_float(mb);
    H.u[e] = (u16)(hb >> 16);
    M.u[e] = (u16)(mb >> 16);
    L.u[e] = (u16)(__float_as_uint(f2) >> 16);
  }
  Bf3 r; r.h = H.b8; r.m = M.b8; r.l = L.b8;
  return r;
}

// swizzled h index: 8-float chunks XORed by row&7 -> conflict-spread reads
__device__ __forceinline__ int hidx(int row, int col) {
  return row * kE + ((((col >> 3) ^ (row & 7)) << 3) | (col & 7));
}

__device__ __forceinline__ float2 ntload2(const float* p) {
  double d = __builtin_nontemporal_load(reinterpret_cast<const double*>(p));
  return *reinterpret_cast<float2*>(&d);
}
__device__ __forceinline__ void ntstore2(float* p, float2 v) {
  __builtin_nontemporal_store(*reinterpret_cast<double*>(&v),
                              reinterpret_cast<double*>(p));
}

// ---- prepass 1: k-major transpose of We2d ----
__global__ void prep_transpose(const float* __restrict__ We2d,
                               float* __restrict__ ws) {
  const int i = blockIdx.x * blockDim.x + threadIdx.x;
  if (i >= kV * kE) return;
  const int k = i / kV, v = i - k * kV;
  ws[kOffWe2dT + i] = We2d[v * kE + k];
}

// ---- prepass 2: token->gi tables (v==128 is the zero-token row) ----
__global__ void prep_tables(const float* __restrict__ Wih,
                            const float* __restrict__ Wd2e,
                            const float* __restrict__ bd2e,
                            const float* __restrict__ bih,
                            float* __restrict__ tab) {
  const int i = blockIdx.x * blockDim.x + threadIdx.x;
  if (i >= 129 * kG3) return;
  const int v = i / kG3, j = i - v * kG3;
  const float* wr = Wih + j * kE;
  float acc = 0.0f;
  if (v < kV) {
    for (int k = 0; k < kE; ++k) acc = fmaf(wr[k], Wd2e[k * kV + v] + bd2e[k], acc);
  } else {
    for (int k = 0; k < kE; ++k) acc = fmaf(wr[k], bd2e[k], acc);
  }
  tab[i] = acc + bih[j];
}

// ---- prepass 3: Whh^T -> bf16 3-way split MFMA B-fragment table ----
// record idx = kg*768 + j (kg = k/8), holds e=0..7 with k = kg*8+e.
__global__ void prep_bsplit(const float* __restrict__ Whh,
                            u16* __restrict__ bt) {
  const int idx = blockIdx.x * blockDim.x + threadIdx.x;
  if (idx >= 32 * kG3) return;
  const int j = idx % kG3;
  const int kg = idx / kG3;
  u16* ph = bt + (size_t)idx * 8;
  u16* pm = ph + kBCount;
  u16* pl = pm + kBCount;
  const float* src = Whh + j * kE + kg * 8;
#pragma unroll
  for (int e = 0; e < 8; ++e) {
    const float f = src[e];
    const unsigned hb = __float_as_uint(f) & 0xffff0000u;
    const float f1 = f - __uint_as_float(hb);
    const unsigned mb = __float_as_uint(f1) & 0xffff0000u;
    const float f2 = f1 - __uint_as_float(mb);
    ph[e] = (u16)(hb >> 16);
    pm[e] = (u16)(mb >> 16);
    pl[e] = (u16)(__float_as_uint(f2) >> 16);
  }
}

// ======== decoder kernel: MFMA GRU + fp32 logits/argmax (order-preserved) ==
__launch_bounds__(1024, 4)
__global__ void dec_kernel(const float* __restrict__ x,
                           const float* __restrict__ unoise,
                           const float* __restrict__ dbhh,
                           const float* __restrict__ dbe2d,
                           const float* __restrict__ ws,
                           u8* __restrict__ tokhist,
                           float* __restrict__ out) {
  const float* We2dT  = ws + kOffWe2dT;
  const float* DecTab = ws + kOffDecTab;
  const u16* Bh_t = (const u16*)(ws + kOffBTabD);
  const u16* Bm_t = Bh_t + kBCount;
  const u16* Bl_t = Bh_t + 2 * kBCount;

  __shared__ __align__(16) float hd[64 * kE];  // 64KB, swizzled
  __shared__ int tokx[64];

  const int tid = (int)threadIdx.x;
  const int w   = tid >> 6;          // 16 waves: mt = w>>2, cs = w&3
  const int jx  = tid & 63;
  const int mt  = w >> 2;
  const int cs  = w & 3;
  const int l15 = jx & 15;
  const int ksub = jx >> 4;
  const int brow0 = (int)blockIdx.x * 64;
  const int arow0 = w << 2;          // this wave argmaxes rows arow0..arow0+3

  for (int i = tid; i < 64 * kE; i += 1024) {
    const int row = i >> 8, col = i & (kE - 1);
    hd[hidx(row, col)] = x[(size_t)(brow0 + row) * kE + col];
  }
  if (tid < 64) tokx[tid] = kV;
  __syncthreads();

  int Nn[4];
  bool alive[4];
#pragma unroll
  for (int r = 0; r < 4; ++r) { Nn[r] = kT; alive[r] = true; }
  const float2 be2 = *(const float2*)(dbe2d + 2 * jx);

  const size_t uttN = (size_t)kB * kT * kV;
  const f32x4 zero4 = {0.0f, 0.0f, 0.0f, 0.0f};

  for (int t = 0; t < kT; ++t) {
    // ---- gh = h @ Whh^T via MFMA (3-way split; order as proven enc) ----
    f32x4 acc[12];
#pragma unroll
    for (int nt = 0; nt < 12; ++nt) acc[nt] = zero4;
#pragma unroll
    for (int kt = 0; kt < 8; ++kt) {
      const int c  = (kt << 2) + ksub;
      const int ar = (mt << 4) + l15;
      const int ch = ((c ^ (ar & 7)) << 3);
      const float4 f0 = *(const float4*)&hd[ar * kE + ch];
      const float4 f1 = *(const float4*)&hd[ar * kE + ch + 4];
      const Bf3 A = split3(f0, f1);
      const int rb = c * kG3;
#pragma unroll
      for (int nt = 0; nt < 12; ++nt) {
        const int col = (nt >> 2) * 256 + (cs << 6) + ((nt & 3) << 4) + l15;
        const int off = (rb + col) * 8;
        const bf16x8 Bh = *reinterpret_cast<const bf16x8*>(Bh_t + off);
        const bf16x8 Bm = *reinterpret_cast<const bf16x8*>(Bm_t + off);
        const bf16x8 Bl = *reinterpret_cast<const bf16x8*>(Bl_t + off);
        acc[nt] = mfma16(A.h, Bh, acc[nt]);
        acc[nt] = mfma16(A.h, Bm, acc[nt]);
        acc[nt] = mfma16(A.m, Bh, acc[nt]);
        acc[nt] = mfma16(A.h, Bl, acc[nt]);
        acc[nt] = mfma16(A.l, Bh, acc[nt]);
        acc[nt] = mfma16(A.m, Bm, acc[nt]);
      }
    }
    __syncthreads();  // all h-reads done; tokx from prev step visible

    // ---- pointwise (formula/order identical to proven kernel) ----
#pragma unroll
    for (int j2 = 0; j2 < 4; ++j2) {
      const int row = (mt << 4) + (ksub << 2) + j2;
      const int tk = tokx[row];
      const float* gp = DecTab + tk * kG3;
#pragma unroll
      for (int s = 0; s < 4; ++s) {
        const int e = (cs << 6) + (s << 4) + l15;
        const float rg = sigmf(gp[e] + acc[s][j2] + dbhh[e]);
        const float zg = sigmf(gp[kE + e] + acc[4 + s][j2] + dbhh[kE + e]);
        const float ng = tanhf(gp[2 * kE + e] + rg * (acc[8 + s][j2] + dbhh[2 * kE + e]));
        const int hx = hidx(row, e);
        const float ho = hd[hx];
        hd[hx] = (1.0f - zg) * ng + zg * ho;
      }
    }
    __syncthreads();  // h_t complete

    // ---- logits (fp32, k-ascending order preserved) + gumbel + argmax ----
    float l0[4], l1[4];
#pragma unroll
    for (int r = 0; r < 4; ++r) { l0[r] = 0.0f; l1[r] = 0.0f; }
#pragma unroll 2
    for (int k8 = 0; k8 < 32; ++k8) {
      float hv[4][8];
#pragma unroll
      for (int r = 0; r < 4; ++r) {
        const int row = arow0 + r;
        const int ch = ((k8 ^ (row & 7)) << 3);
        const float4 fa = *(const float4*)&hd[row * kE + ch];
        const float4 fb = *(const float4*)&hd[row * kE + ch + 4];
        hv[r][0] = fa.x; hv[r][1] = fa.y; hv[r][2] = fa.z; hv[r][3] = fa.w;
        hv[r][4] = fb.x; hv[r][5] = fb.y; hv[r][6] = fb.z; hv[r][7] = fb.w;
      }
#pragma unroll
      for (int e = 0; e < 8; ++e) {
        const float2 wv = *(const float2*)(We2dT + (k8 * 8 + e) * kV + 2 * jx);
#pragma unroll
        for (int r = 0; r < 4; ++r) {
          l0[r] = fmaf(hv[r][e], wv.x, l0[r]);
          l1[r] = fmaf(hv[r][e], wv.y, l1[r]);
        }
      }
    }
    const float* up = unoise + ((size_t)t * kB + brow0 + arow0) * kV + 2 * jx;
#pragma unroll
    for (int r = 0; r < 4; ++r) {
      const float2 u = ntload2(up + (size_t)r * kV);
      const float a0 = l0[r] + be2.x + gumbelf(u.x);
      const float a1 = l1[r] + be2.y + gumbelf(u.y);
      float mv; int mi;
      if (a1 > a0) { mv = a1; mi = 2 * jx + 1; } else { mv = a0; mi = 2 * jx; }
#pragma unroll
      for (int off = 32; off >= 1; off >>= 1) {
        const float ov = __shfl_xor(mv, off, 64);
        const int   oi = __shfl_xor(mi, off, 64);
        if (ov > mv || (ov == mv && oi < mi)) { mv = ov; mi = oi; }
      }
      const bool ended = (mi == 0);
      if (ended) Nn[r] = (Nn[r] < t) ? Nn[r] : t;
      const bool anew = alive[r] && !ended;
      alive[r] = anew;
      const int tokv = __builtin_amdgcn_readfirstlane(anew ? mi : kV);
      if (jx == r) {
        tokx[arow0 + r] = tokv;
        tokhist[(size_t)t * kB + brow0 + arow0 + r] = (u8)tokv;
      }
      float2 pr;
      pr.x = (anew && mi == 2 * jx) ? 1.0f : 0.0f;
      pr.y = (anew && mi == 2 * jx + 1) ? 1.0f : 0.0f;
      ntstore2(out + ((size_t)(brow0 + arow0 + r) * kT + t) * kV + 2 * jx, pr);
    }
    // tokx written here is read after next step's post-MFMA barrier.
  }

  // ---- N output ----
#pragma unroll
  for (int r = 0; r < 4; ++r)
    if (jx == r) out[uttN + brow0 + arow0 + r] = (float)Nn[r];
}

// ======== encoder kernel: same tiling, tokens from tokhist ================
__launch_bounds__(1024, 4)
__global__ void enc_kernel(const float* __restrict__ ebhh,
                           const float* __restrict__ ws,
                           const u8* __restrict__ tokhist,
                           float* __restrict__ out) {
  const float* EncTab = ws + kOffEncTab;
  const u16* Bh_t = (const u16*)(ws + kOffBTabE);
  const u16* Bm_t = Bh_t + kBCount;
  const u16* Bl_t = Bh_t + 2 * kBCount;

  __shared__ __align__(16) float hd[64 * kE];  // 64KB, swizzled

  const int tid = (int)threadIdx.x;
  const int w   = tid >> 6;
  const int jx  = tid & 63;
  const int mt  = w >> 2;
  const int cs  = w & 3;
  const int l15 = jx & 15;
  const int ksub = jx >> 4;
  const int brow0 = (int)blockIdx.x * 64;

  for (int i = tid; i < 64 * kE; i += 1024) hd[i] = 0.0f;
  __syncthreads();

  const size_t uttN = (size_t)kB * kT * kV;
  const f32x4 zero4 = {0.0f, 0.0f, 0.0f, 0.0f};

  for (int t = 0; t < kT; ++t) {
    f32x4 acc[12];
#pragma unroll
    for (int nt = 0; nt < 12; ++nt) acc[nt] = zero4;
#pragma unroll
    for (int kt = 0; kt < 8; ++kt) {
      const int c  = (kt << 2) + ksub;
      const int ar = (mt << 4) + l15;
      const int ch = ((c ^ (ar & 7)) << 3);
      const float4 f0 = *(const float4*)&hd[ar * kE + ch];
      const float4 f1 = *(const float4*)&hd[ar * kE + ch + 4];
      const Bf3 A = split3(f0, f1);
      const int rb = c * kG3;
#pragma unroll
      for (int nt = 0; nt < 12; ++nt) {
        const int col = (nt >> 2) * 256 + (cs << 6) + ((nt & 3) << 4) + l15;
        const int off = (rb + col) * 8;
        const bf16x8 Bh = *reinterpret_cast<const bf16x8*>(Bh_t + off);
        const bf16x8 Bm = *reinterpret_cast<const bf16x8*>(Bm_t + off);
        const bf16x8 Bl = *reinterpret_cast<const bf16x8*>(Bl_t + off);
        acc[nt] = mfma16(A.h, Bh, acc[nt]);
        acc[nt] = mfma16(A.h, Bm, acc[nt]);
        acc[nt] = mfma16(A.m, Bh, acc[nt]);
        acc[nt] = mfma16(A.h, Bl, acc[nt]);
        acc[nt] = mfma16(A.l, Bh, acc[nt]);
        acc[nt] = mfma16(A.m, Bm, acc[nt]);
      }
    }
    __syncthreads();  // all h-reads done

#pragma unroll
    for (int j2 = 0; j2 < 4; ++j2) {
      const int row = (mt << 4) + (ksub << 2) + j2;
      const int tk = (int)tokhist[(size_t)t * kB + brow0 + row];
      const float* gp = EncTab + tk * kG3;
#pragma unroll
      for (int s = 0; s < 4; ++s) {
        const int e = (cs << 6) + (s << 4) + l15;
        const float rg = sigmf(gp[e] + acc[s][j2] + ebhh[e]);
        const float zg = sigmf(gp[kE + e] + acc[4 + s][j2] + ebhh[kE + e]);
        const float ng = tanhf(gp[2 * kE + e] + rg * (acc[8 + s][j2] + ebhh[2 * kE + e]));
        const int hx = hidx(row, e);
        const float ho = hd[hx];
        hd[hx] = (1.0f - zg) * ng + zg * ho;
      }
    }
    __syncthreads();  // h_t complete before next step's reads
  }

  // ---- reconst = final h ----
  for (int i = tid; i < 64 * kE; i += 1024) {
    const int row = i >> 8, col = i & (kE - 1);
    out[uttN + kB + (size_t)(brow0 + row) * kE + col] = hd[hidx(row, col)];
  }
}

extern "C" void kernel_launch(void* const* d_in, const int* in_sizes, int n_in,
                              void* d_out, int out_size, void* d_ws, size_t ws_size,
                              hipStream_t stream) {
  (void)in_sizes; (void)n_in; (void)out_size; (void)ws_size;
  const float* x      = (const float*)d_in[0];
  // d_in[1] = global_idxes (unused by reference)
  const float* unoise = (const float*)d_in[2];
  const float* dWd2e  = (const float*)d_in[3];
  const float* dbd2e  = (const float*)d_in[4];
  const float* dWih   = (const float*)d_in[5];
  const float* dWhh   = (const float*)d_in[6];
  const float* dbih   = (const float*)d_in[7];
  const float* dbhh   = (const float*)d_in[8];
  const float* dWe2d  = (const float*)d_in[9];
  const float* dbe2d  = (const float*)d_in[10];
  const float* eWd2e  = (const float*)d_in[11];
  const float* ebd2e  = (const float*)d_in[12];
  const float* eWih   = (const float*)d_in[13];
  const float* eWhh   = (const float*)d_in[14];
  const float* ebih   = (const float*)d_in[15];
  const float* ebhh   = (const float*)d_in[16];
  float* ws = (float*)d_ws;  // needs 3,545,088 bytes (~3.4 MB)
  u8* tokhist = (u8*)(ws + kOffTok);

  prep_transpose<<<(kV * kE + 255) / 256, 256, 0, stream>>>(dWe2d, ws);
  prep_tables<<<(129 * kG3 + 255) / 256, 256, 0, stream>>>(
      dWih, dWd2e, dbd2e, dbih, ws + kOffDecTab);
  prep_tables<<<(129 * kG3 + 255) / 256, 256, 0, stream>>>(
      eWih, eWd2e, ebd2e, ebih, ws + kOffEncTab);
  prep_bsplit<<<(32 * kG3 + 255) / 256, 256, 0, stream>>>(
      eWhh, (u16*)(ws + kOffBTabE));
  prep_bsplit<<<(32 * kG3 + 255) / 256, 256, 0, stream>>>(
      dWhh, (u16*)(ws + kOffBTabD));
  dec_kernel<<<kB / 64, 1024, 0, stream>>>(
      x, unoise, dbhh, dbe2d, ws, tokhist, (float*)d_out);
  enc_kernel<<<kB / 64, 1024, 0, stream>>>(
      ebhh, ws, tokhist, (float*)d_out);
}

// Round 10
// 11343.903 us; speedup vs baseline: 1.1227x; 1.1227x over previous
//
#include <hip/hip_runtime.h>

// GumbelDecoderEncoder: B=16384, E=256, V=128, T=16, TAU=1.
// Key facts exploited:
//  * y is numerically EXACTLY one-hot or zero -> input matmuls are table
//    lookups (DecTab/EncTab row 128 = zero-token case).
//  * argmax(softmax((l+g)/tau)) == argmax(l+g).
//  * Encoder sieve can never fire: reconst = final encoder state.
// History: every failed round (R3/R4/R6/R7/R9) = same disease: per-wave
// register demand > granted arch VGPRs -> scratch spills (GB-scale FETCH/
// WRITE, L2 thrashed). R9 proved the MFMA-GRU decoder numerics are SAFE
// (absmax bit-identical, zero argmax flips) but launch_bounds(1024,4)
// forced VGPR=64 -> spills.
// R10: same proven structure, pressure-engineered:
//  * 32 rows/block, 512 thr (8 waves), 512 blocks; wave = 1 Mtile x 12
//    Ntiles -> acc 48 + A 12 + B 12 + misc ~80 arch: fits 128 with slack.
//  * __launch_bounds__(512,1): weakest constraint -> budget >=256 under
//    either interpretation of arg2; no forced spill.
//  * All math byte-identical to R9 (MFMA product order hh,hm,mh,hl,lh,mm;
//    fp32 logits k-ascending; argmax shuffle) -> absmax must stay pinned.
// ws: 886272 floats = 3,545,088 bytes.

namespace {
constexpr int kB  = 16384;
constexpr int kE  = 256;
constexpr int kV  = 128;
constexpr int kT  = 16;
constexpr int kG3 = 768;
constexpr int kR  = 32;   // rows per block

constexpr int kOffWe2dT  = 0;                        // [256][128] f32
constexpr int kOffDecTab = kV * kE;                  // [129][768] f32
constexpr int kOffEncTab = kOffDecTab + 129 * kG3;   // [129][768] f32
constexpr int kOffBTabE  = kOffEncTab + 129 * kG3;   // enc Whh 3-split (u16)
constexpr int kBCount    = 32 * kG3 * 8;             // 196608 u16 per level
constexpr int kOffBTabD  = kOffBTabE + (3 * kBCount) / 2;  // dec Whh 3-split
constexpr int kOffTok    = kOffBTabD + (3 * kBCount) / 2;  // [16][16384] u8
// ws floats: 820736 + 65536 = 886272  (3,545,088 bytes)
}

typedef short bf16x8 __attribute__((ext_vector_type(8)));  // 8 bf16 (4 VGPRs)
typedef float f32x4  __attribute__((ext_vector_type(4)));
typedef unsigned short u16;
typedef unsigned char u8;

__device__ __forceinline__ float sigmf(float v) { return 1.0f / (1.0f + expf(-v)); }
__device__ __forceinline__ float gumbelf(float u) {
  return -logf(-logf(u + 1e-10f) + 1e-10f);
}

__device__ __forceinline__ f32x4 mfma16(bf16x8 a, bf16x8 b, f32x4 c) {
  return __builtin_amdgcn_mfma_f32_16x16x32_bf16(a, b, c, 0, 0, 0);
}

struct Bf3 { bf16x8 h, m, l; };

// exact 3-way bf16 split: f = hi + mid + f2 (exact); lo = trunc-bf16(f2).
__device__ __forceinline__ Bf3 split3(float4 a, float4 b) {
  const float v[8] = {a.x, a.y, a.z, a.w, b.x, b.y, b.z, b.w};
  union { bf16x8 b8; u16 u[8]; } H, M, L;
#pragma unroll
  for (int e = 0; e < 8; ++e) {
    const float f = v[e];
    const unsigned hb = __float_as_uint(f) & 0xffff0000u;
    const float f1 = f - __uint_as_float(hb);
    const unsigned mb = __float_as_uint(f1) & 0xffff0000u;
    const float f2 = f1 - __uint_as_float(mb);
    H.u[e] = (u16)(hb >> 16);
    M.u[e] = (u16)(mb >> 16);
    L.u[e] = (u16)(__float_as_uint(f2) >> 16);
  }
  Bf3 r; r.h = H.b8; r.m = M.b8; r.l = L.b8;
  return r;
}

// swizzled h index: 8-float chunks XORed by row&7 -> conflict-spread reads
__device__ __forceinline__ int hidx(int row, int col) {
  return row * kE + ((((col >> 3) ^ (row & 7)) << 3) | (col & 7));
}

__device__ __forceinline__ float2 ntload2(const float* p) {
  double d = __builtin_nontemporal_load(reinterpret_cast<const double*>(p));
  return *reinterpret_cast<float2*>(&d);
}
__device__ __forceinline__ void ntstore2(float* p, float2 v) {
  __builtin_nontemporal_store(*reinterpret_cast<double*>(&v),
                              reinterpret_cast<double*>(p));
}

// ---- prepass 1: k-major transpose of We2d ----
__global__ void prep_transpose(const float* __restrict__ We2d,
                               float* __restrict__ ws) {
  const int i = blockIdx.x * blockDim.x + threadIdx.x;
  if (i >= kV * kE) return;
  const int k = i / kV, v = i - k * kV;
  ws[kOffWe2dT + i] = We2d[v * kE + k];
}

// ---- prepass 2: token->gi tables (v==128 is the zero-token row) ----
__global__ void prep_tables(const float* __restrict__ Wih,
                            const float* __restrict__ Wd2e,
                            const float* __restrict__ bd2e,
                            const float* __restrict__ bih,
                            float* __restrict__ tab) {
  const int i = blockIdx.x * blockDim.x + threadIdx.x;
  if (i >= 129 * kG3) return;
  const int v = i / kG3, j = i - v * kG3;
  const float* wr = Wih + j * kE;
  float acc = 0.0f;
  if (v < kV) {
    for (int k = 0; k < kE; ++k) acc = fmaf(wr[k], Wd2e[k * kV + v] + bd2e[k], acc);
  } else {
    for (int k = 0; k < kE; ++k) acc = fmaf(wr[k], bd2e[k], acc);
  }
  tab[i] = acc + bih[j];
}

// ---- prepass 3: Whh^T -> bf16 3-way split MFMA B-fragment table ----
// record idx = kg*768 + j (kg = k/8), holds e=0..7 with k = kg*8+e.
__global__ void prep_bsplit(const float* __restrict__ Whh,
                            u16* __restrict__ bt) {
  const int idx = blockIdx.x * blockDim.x + threadIdx.x;
  if (idx >= 32 * kG3) return;
  const int j = idx % kG3;
  const int kg = idx / kG3;
  u16* ph = bt + (size_t)idx * 8;
  u16* pm = ph + kBCount;
  u16* pl = pm + kBCount;
  const float* src = Whh + j * kE + kg * 8;
#pragma unroll
  for (int e = 0; e < 8; ++e) {
    const float f = src[e];
    const unsigned hb = __float_as_uint(f) & 0xffff0000u;
    const float f1 = f - __uint_as_float(hb);
    const unsigned mb = __float_as_uint(f1) & 0xffff0000u;
    const float f2 = f1 - __uint_as_float(mb);
    ph[e] = (u16)(hb >> 16);
    pm[e] = (u16)(mb >> 16);
    pl[e] = (u16)(__float_as_uint(f2) >> 16);
  }
}

// ======== decoder kernel: MFMA GRU + fp32 logits/argmax (order-preserved) ==
__launch_bounds__(512, 1)
__global__ void dec_kernel(const float* __restrict__ x,
                           const float* __restrict__ unoise,
                           const float* __restrict__ dbhh,
                           const float* __restrict__ dbe2d,
                           const float* __restrict__ ws,
                           u8* __restrict__ tokhist,
                           float* __restrict__ out) {
  const float* We2dT  = ws + kOffWe2dT;
  const float* DecTab = ws + kOffDecTab;
  const u16* Bh_t = (const u16*)(ws + kOffBTabD);
  const u16* Bm_t = Bh_t + kBCount;
  const u16* Bl_t = Bh_t + 2 * kBCount;

  __shared__ __align__(16) float hd[kR * kE];  // 32KB, swizzled
  __shared__ int tokx[kR];

  const int tid = (int)threadIdx.x;
  const int w   = tid >> 6;          // 8 waves: mt = w>>2 (0..1), cs = w&3
  const int jx  = tid & 63;
  const int mt  = w >> 2;
  const int cs  = w & 3;
  const int l15 = jx & 15;
  const int ksub = jx >> 4;
  const int brow0 = (int)blockIdx.x * kR;
  const int arow0 = w << 2;          // this wave argmaxes rows arow0..arow0+3

  for (int i = tid; i < kR * kE; i += 512) {
    const int row = i >> 8, col = i & (kE - 1);
    hd[hidx(row, col)] = x[(size_t)(brow0 + row) * kE + col];
  }
  if (tid < kR) tokx[tid] = kV;
  __syncthreads();

  int Nn[4];
  bool alive[4];
#pragma unroll
  for (int r = 0; r < 4; ++r) { Nn[r] = kT; alive[r] = true; }
  const float2 be2 = *(const float2*)(dbe2d + 2 * jx);

  const size_t uttN = (size_t)kB * kT * kV;
  const f32x4 zero4 = {0.0f, 0.0f, 0.0f, 0.0f};

  for (int t = 0; t < kT; ++t) {
    // ---- gh = h @ Whh^T via MFMA (3-way split; order as proven) ----
    f32x4 acc[12];
#pragma unroll
    for (int nt = 0; nt < 12; ++nt) acc[nt] = zero4;
#pragma unroll
    for (int kt = 0; kt < 8; ++kt) {
      const int c  = (kt << 2) + ksub;
      const int ar = (mt << 4) + l15;
      const int ch = ((c ^ (ar & 7)) << 3);
      const float4 f0 = *(const float4*)&hd[ar * kE + ch];
      const float4 f1 = *(const float4*)&hd[ar * kE + ch + 4];
      const Bf3 A = split3(f0, f1);
      const int rb = c * kG3;
#pragma unroll
      for (int nt = 0; nt < 12; ++nt) {
        const int col = (nt >> 2) * 256 + (cs << 6) + ((nt & 3) << 4) + l15;
        const int off = (rb + col) * 8;
        const bf16x8 Bh = *reinterpret_cast<const bf16x8*>(Bh_t + off);
        const bf16x8 Bm = *reinterpret_cast<const bf16x8*>(Bm_t + off);
        const bf16x8 Bl = *reinterpret_cast<const bf16x8*>(Bl_t + off);
        acc[nt] = mfma16(A.h, Bh, acc[nt]);
        acc[nt] = mfma16(A.h, Bm, acc[nt]);
        acc[nt] = mfma16(A.m, Bh, acc[nt]);
        acc[nt] = mfma16(A.h, Bl, acc[nt]);
        acc[nt] = mfma16(A.l, Bh, acc[nt]);
        acc[nt] = mfma16(A.m, Bm, acc[nt]);
      }
    }
    __syncthreads();  // all h-reads done; tokx from prev step visible

    // ---- pointwise (formula/order identical to proven kernel) ----
#pragma unroll
    for (int j2 = 0; j2 < 4; ++j2) {
      const int row = (mt << 4) + (ksub << 2) + j2;
      const int tk = tokx[row];
      const float* gp = DecTab + tk * kG3;
#pragma unroll
      for (int s = 0; s < 4; ++s) {
        const int e = (cs << 6) + (s << 4) + l15;
        const float rg = sigmf(gp[e] + acc[s][j2] + dbhh[e]);
        const float zg = sigmf(gp[kE + e] + acc[4 + s][j2] + dbhh[kE + e]);
        const float ng = tanhf(gp[2 * kE + e] + rg * (acc[8 + s][j2] + dbhh[2 * kE + e]));
        const int hx = hidx(row, e);
        const float ho = hd[hx];
        hd[hx] = (1.0f - zg) * ng + zg * ho;
      }
    }
    __syncthreads();  // h_t complete

    // ---- logits (fp32, k-ascending order preserved) + gumbel + argmax ----
    float l0[4], l1[4];
#pragma unroll
    for (int r = 0; r < 4; ++r) { l0[r] = 0.0f; l1[r] = 0.0f; }
#pragma unroll 2
    for (int k8 = 0; k8 < 32; ++k8) {
      float hv[4][8];
#pragma unroll
      for (int r = 0; r < 4; ++r) {
        const int row = arow0 + r;
        const int ch = ((k8 ^ (row & 7)) << 3);
        const float4 fa = *(const float4*)&hd[row * kE + ch];
        const float4 fb = *(const float4*)&hd[row * kE + ch + 4];
        hv[r][0] = fa.x; hv[r][1] = fa.y; hv[r][2] = fa.z; hv[r][3] = fa.w;
        hv[r][4] = fb.x; hv[r][5] = fb.y; hv[r][6] = fb.z; hv[r][7] = fb.w;
      }
#pragma unroll
      for (int e = 0; e < 8; ++e) {
        const float2 wv = *(const float2*)(We2dT + (k8 * 8 + e) * kV + 2 * jx);
#pragma unroll
        for (int r = 0; r < 4; ++r) {
          l0[r] = fmaf(hv[r][e], wv.x, l0[r]);
          l1[r] = fmaf(hv[r][e], wv.y, l1[r]);
        }
      }
    }
    const float* up = unoise + ((size_t)t * kB + brow0 + arow0) * kV + 2 * jx;
#pragma unroll
    for (int r = 0; r < 4; ++r) {
      const float2 u = ntload2(up + (size_t)r * kV);
      const float a0 = l0[r] + be2.x + gumbelf(u.x);
      const float a1 = l1[r] + be2.y + gumbelf(u.y);
      float mv; int mi;
      if (a1 > a0) { mv = a1; mi = 2 * jx + 1; } else { mv = a0; mi = 2 * jx; }
#pragma unroll
      for (int off = 32; off >= 1; off >>= 1) {
        const float ov = __shfl_xor(mv, off, 64);
        const int   oi = __shfl_xor(mi, off, 64);
        if (ov > mv || (ov == mv && oi < mi)) { mv = ov; mi = oi; }
      }
      const bool ended = (mi == 0);
      if (ended) Nn[r] = (Nn[r] < t) ? Nn[r] : t;
      const bool anew = alive[r] && !ended;
      alive[r] = anew;
      const int tokv = __builtin_amdgcn_readfirstlane(anew ? mi : kV);
      if (jx == r) {
        tokx[arow0 + r] = tokv;
        tokhist[(size_t)t * kB + brow0 + arow0 + r] = (u8)tokv;
      }
      float2 pr;
      pr.x = (anew && mi == 2 * jx) ? 1.0f : 0.0f;
      pr.y = (anew && mi == 2 * jx + 1) ? 1.0f : 0.0f;
      ntstore2(out + ((size_t)(brow0 + arow0 + r) * kT + t) * kV + 2 * jx, pr);
    }
    // tokx written here is read after next step's post-MFMA barrier.
  }

  // ---- N output ----
#pragma unroll
  for (int r = 0; r < 4; ++r)
    if (jx == r) out[uttN + brow0 + arow0 + r] = (float)Nn[r];
}

// ======== encoder kernel: same tiling, tokens from tokhist ================
__launch_bounds__(512, 1)
__global__ void enc_kernel(const float* __restrict__ ebhh,
                           const float* __restrict__ ws,
                           const u8* __restrict__ tokhist,
                           float* __restrict__ out) {
  const float* EncTab = ws + kOffEncTab;
  const u16* Bh_t = (const u16*)(ws + kOffBTabE);
  const u16* Bm_t = Bh_t + kBCount;
  const u16* Bl_t = Bh_t + 2 * kBCount;

  __shared__ __align__(16) float hd[kR * kE];  // 32KB, swizzled

  const int tid = (int)threadIdx.x;
  const int w   = tid >> 6;
  const int jx  = tid & 63;
  const int mt  = w >> 2;
  const int cs  = w & 3;
  const int l15 = jx & 15;
  const int ksub = jx >> 4;
  const int brow0 = (int)blockIdx.x * kR;

  for (int i = tid; i < kR * kE; i += 512) hd[i] = 0.0f;
  __syncthreads();

  const size_t uttN = (size_t)kB * kT * kV;
  const f32x4 zero4 = {0.0f, 0.0f, 0.0f, 0.0f};

  for (int t = 0; t < kT; ++t) {
    f32x4 acc[12];
#pragma unroll
    for (int nt = 0; nt < 12; ++nt) acc[nt] = zero4;
#pragma unroll
    for (int kt = 0; kt < 8; ++kt) {
      const int c  = (kt << 2) + ksub;
      const int ar = (mt << 4) + l15;
      const int ch = ((c ^ (ar & 7)) << 3);
      const float4 f0 = *(const float4*)&hd[ar * kE + ch];
      const float4 f1 = *(const float4*)&hd[ar * kE + ch + 4];
      const Bf3 A = split3(f0, f1);
      const int rb = c * kG3;
#pragma unroll
      for (int nt = 0; nt < 12; ++nt) {
        const int col = (nt >> 2) * 256 + (cs << 6) + ((nt & 3) << 4) + l15;
        const int off = (rb + col) * 8;
        const bf16x8 Bh = *reinterpret_cast<const bf16x8*>(Bh_t + off);
        const bf16x8 Bm = *reinterpret_cast<const bf16x8*>(Bm_t + off);
        const bf16x8 Bl = *reinterpret_cast<const bf16x8*>(Bl_t + off);
        acc[nt] = mfma16(A.h, Bh, acc[nt]);
        acc[nt] = mfma16(A.h, Bm, acc[nt]);
        acc[nt] = mfma16(A.m, Bh, acc[nt]);
        acc[nt] = mfma16(A.h, Bl, acc[nt]);
        acc[nt] = mfma16(A.l, Bh, acc[nt]);
        acc[nt] = mfma16(A.m, Bm, acc[nt]);
      }
    }
    __syncthreads();  // all h-reads done

#pragma unroll
    for (int j2 = 0; j2 < 4; ++j2) {
      const int row = (mt << 4) + (ksub << 2) + j2;
      const int tk = (int)tokhist[(size_t)t * kB + brow0 + row];
      const float* gp = EncTab + tk * kG3;
#pragma unroll
      for (int s = 0; s < 4; ++s) {
        const int e = (cs << 6) + (s << 4) + l15;
        const float rg = sigmf(gp[e] + acc[s][j2] + ebhh[e]);
        const float zg = sigmf(gp[kE + e] + acc[4 + s][j2] + ebhh[kE + e]);
        const float ng = tanhf(gp[2 * kE + e] + rg * (acc[8 + s][j2] + ebhh[2 * kE + e]));
        const int hx = hidx(row, e);
        const float ho = hd[hx];
        hd[hx] = (1.0f - zg) * ng + zg * ho;
      }
    }
    __syncthreads();  // h_t complete before next step's reads
  }

  // ---- reconst = final h ----
  for (int i = tid; i < kR * kE; i += 512) {
    const int row = i >> 8, col = i & (kE - 1);
    out[uttN + kB + (size_t)(brow0 + row) * kE + col] = hd[hidx(row, col)];
  }
}

extern "C" void kernel_launch(void* const* d_in, const int* in_sizes, int n_in,
                              void* d_out, int out_size, void* d_ws, size_t ws_size,
                              hipStream_t stream) {
  (void)in_sizes; (void)n_in; (void)out_size; (void)ws_size;
  const float* x      = (const float*)d_in[0];
  // d_in[1] = global_idxes (unused by reference)
  const float* unoise = (const float*)d_in[2];
  const float* dWd2e  = (const float*)d_in[3];
  const float* dbd2e  = (const float*)d_in[4];
  const float* dWih   = (const float*)d_in[5];
  const float* dWhh   = (const float*)d_in[6];
  const float* dbih   = (const float*)d_in[7];
  const float* dbhh   = (const float*)d_in[8];
  const float* dWe2d  = (const float*)d_in[9];
  const float* dbe2d  = (const float*)d_in[10];
  const float* eWd2e  = (const float*)d_in[11];
  const float* ebd2e  = (const float*)d_in[12];
  const float* eWih   = (const float*)d_in[13];
  const float* eWhh   = (const float*)d_in[14];
  const float* ebih   = (const float*)d_in[15];
  const float* ebhh   = (const float*)d_in[16];
  float* ws = (float*)d_ws;  // needs 3,545,088 bytes (~3.4 MB)
  u8* tokhist = (u8*)(ws + kOffTok);

  prep_transpose<<<(kV * kE + 255) / 256, 256, 0, stream>>>(dWe2d, ws);
  prep_tables<<<(129 * kG3 + 255) / 256, 256, 0, stream>>>(
      dWih, dWd2e, dbd2e, dbih, ws + kOffDecTab);
  prep_tables<<<(129 * kG3 + 255) / 256, 256, 0, stream>>>(
      eWih, eWd2e, ebd2e, ebih, ws + kOffEncTab);
  prep_bsplit<<<(32 * kG3 + 255) / 256, 256, 0, stream>>>(
      eWhh, (u16*)(ws + kOffBTabE));
  prep_bsplit<<<(32 * kG3 + 255) / 256, 256, 0, stream>>>(
      dWhh, (u16*)(ws + kOffBTabD));
  dec_kernel<<<kB / kR, 512, 0, stream>>>(
      x, unoise, dbhh, dbe2d, ws, tokhist, (float*)d_out);
  enc_kernel<<<kB / kR, 512, 0, stream>>>(
      ebhh, ws, tokhist, (float*)d_out);
}